// Round 4
// baseline (132.353 us; speedup 1.0000x reference)
//
#include <hip/hip_runtime.h>
#include <hip/hip_bf16.h>

namespace {

constexpr int kS  = 2048;
constexpr int kD  = 128;
constexpr int kKB = 128;            // kv rows per tile
constexpr int kNT = kS / kKB;       // 16 tiles
constexpr int kStr = 136;           // LDS row stride in ushorts (272B -> superbank step 1)
constexpr int kABytes = 2 * 128 * kStr * 2;   // 69632 per (K or V) double-buffered array
constexpr int kSmem = 2 * kABytes;            // 139264

typedef __attribute__((ext_vector_type(8)))  short bf16x8;
typedef __attribute__((ext_vector_type(16))) float f32x16;
typedef __attribute__((ext_vector_type(4)))  unsigned int u32x4;

__device__ inline unsigned short f2bf(float f) {
  return __builtin_bit_cast(unsigned short, __float2bfloat16(f));
}
__device__ inline unsigned pk2(float lo, float hi) {
  return (unsigned)f2bf(lo) | ((unsigned)f2bf(hi) << 16);
}
__device__ inline float fexp2(float x) { return __builtin_amdgcn_exp2f(x); }

__global__ __launch_bounds__(1024, 4)   // 16 waves/CU -> 128 VGPR cap (NOT the default 64)
void attn_fwd(const float* __restrict__ Q, const float* __restrict__ K,
              const float* __restrict__ V, float* __restrict__ O)
{
  __shared__ __align__(16) unsigned char smem[kSmem];
  auto KL = reinterpret_cast<unsigned short (*)[128][kStr]>(smem);            // [2][128][136]
  auto VL = reinterpret_cast<unsigned short (*)[128][kStr]>(smem + kABytes);  // [2][128][136] (V^T, swizzled)

  const int tid  = threadIdx.x;
  const int wv   = tid >> 6;
  const int qg   = wv & 3;          // q-group: 32 q-rows
  const int ksp  = wv >> 2;         // k-split: 32 of 128 kv-rows
  const int lane = tid & 63;
  const int l31  = lane & 31;
  const int hi   = lane >> 5;

  // XCD-locality: 2 batches per XCD
  const int bid   = blockIdx.x;
  const int xcd   = bid & 7;
  const int slot  = bid >> 3;
  const int batch = xcd * 2 + (slot >> 4);
  const int qtile = slot & 15;

  const float* Qb = Q + (size_t)batch * kS * kD;
  const float* Kb = K + (size_t)batch * kS * kD;
  const float* Vb = V + (size_t)batch * kS * kD;
  float*       Ob = O + (size_t)batch * kS * kD;

  const int qrow0 = qtile * 128 + qg * 32;

  // ---- Q fragments as MFMA B-operand: col q = l31, rows d = c*16 + hi*8 + e
  constexpr float kQScale = 0.08838834764831845f * 1.4426950408889634f; // 1/sqrt(128) * log2(e)
  bf16x8 qf[8];
#pragma unroll
  for (int c = 0; c < 8; ++c) {
    const float* p = Qb + (size_t)(qrow0 + l31) * kD + c * 16 + hi * 8;
    float4 a = *reinterpret_cast<const float4*>(p);
    float4 b = *reinterpret_cast<const float4*>(p + 4);
    bf16x8 f;
    f[0] = (short)f2bf(a.x * kQScale);
    f[1] = (short)f2bf(a.y * kQScale);
    f[2] = (short)f2bf(a.z * kQScale);
    f[3] = (short)f2bf(a.w * kQScale);
    f[4] = (short)f2bf(b.x * kQScale);
    f[5] = (short)f2bf(b.y * kQScale);
    f[6] = (short)f2bf(b.z * kQScale);
    f[7] = (short)f2bf(b.w * kQScale);
    qf[c] = f;
  }

  // ---- staging (1024 threads stage the full 128x128 K and V tiles)
  const int krow = tid >> 5, c4 = tid & 31;
  float4 kreg[4];
  float4 va[2], vb[2];

  auto loadK = [&](int t) {
    const float* ks = Kb + (size_t)t * kKB * kD;
#pragma unroll
    for (int i = 0; i < 4; ++i)
      kreg[i] = *reinterpret_cast<const float4*>(ks + (size_t)(i * 32 + krow) * kD + c4 * 4);
  };
  auto storeK = [&](int b) {
#pragma unroll
    for (int i = 0; i < 4; ++i) {
      ushort4 c;
      c.x = f2bf(kreg[i].x); c.y = f2bf(kreg[i].y);
      c.z = f2bf(kreg[i].z); c.w = f2bf(kreg[i].w);
      *reinterpret_cast<ushort4*>(&KL[b][i * 32 + krow][c4 * 4]) = c;
    }
  };
  auto loadV = [&](int t) {
    const float* vs = Vb + (size_t)t * kKB * kD;
#pragma unroll
    for (int i = 0; i < 2; ++i) {
      const int kp = i * 32 + krow;           // k-pair index 0..63
      va[i] = *reinterpret_cast<const float4*>(vs + (size_t)(2 * kp) * kD + c4 * 4);
      vb[i] = *reinterpret_cast<const float4*>(vs + (size_t)(2 * kp + 1) * kD + c4 * 4);
    }
  };
  auto storeV = [&](int b) {
#pragma unroll
    for (int i = 0; i < 2; ++i) {
      const int kp = i * 32 + krow;
      const int chunk = kp >> 2;              // (2kp)>>3
      const int koff  = (2 * kp) & 7;
      float a0[4] = {va[i].x, va[i].y, va[i].z, va[i].w};
      float a1[4] = {vb[i].x, vb[i].y, vb[i].z, vb[i].w};
#pragma unroll
      for (int j = 0; j < 4; ++j) {
        const int d = c4 * 4 + j;
        const int csw = chunk ^ ((d >> 3) & 15);
        ushort2 c;
        c.x = f2bf(a0[j]); c.y = f2bf(a1[j]);
        *reinterpret_cast<ushort2*>(&VL[b][d][csw * 8 + koff]) = c;
      }
    }
  };

  // ---- flash state: acc[dt] rows d=(r&3)+8*(r>>2)+4*hi (+32*dt), col q=l31
  f32x16 acc[4];
#pragma unroll
  for (int dt = 0; dt < 4; ++dt)
#pragma unroll
    for (int r = 0; r < 16; ++r) acc[dt][r] = 0.f;
  float mrun = -1e30f, lrun = 0.f;

  loadK(0); loadV(0);
  storeK(0); storeV(0);
  __syncthreads();

  for (int t = 0; t < kNT; ++t) {
    const int cur = t & 1;
    const bool pre = (t + 1 < kNT);
    if (pre) loadK(t + 1);

    // ---- QK^T swapped: S^T = K_slice . Qs^T ; rows k in regs, col q = l31
    f32x16 sc;
#pragma unroll
    for (int r = 0; r < 16; ++r) sc[r] = 0.f;
    __builtin_amdgcn_s_setprio(1);
#pragma unroll
    for (int c = 0; c < 8; ++c) {
      bf16x8 kf = *reinterpret_cast<const bf16x8*>(&KL[cur][ksp * 32 + l31][c * 16 + hi * 8]);
      sc = __builtin_amdgcn_mfma_f32_32x32x16_bf16(kf, qf[c], sc, 0, 0, 0);
    }
    __builtin_amdgcn_s_setprio(0);

    if (pre) { storeK(cur ^ 1); loadV(t + 1); }

    // ---- lane-local online softmax (k in regs; one xor-32 to merge hi halves)
    float mt = sc[0];
#pragma unroll
    for (int r = 1; r < 16; ++r) mt = fmaxf(mt, sc[r]);
    mt = fmaxf(mt, __shfl_xor(mt, 32));
    const float growth = mt - mrun;
    if (!__all(growth <= 8.0f)) {             // T13 defer-max
      const float mn = fmaxf(mrun, mt);
      const float corr = fexp2(mrun - mn);
      lrun *= corr;
#pragma unroll
      for (int dt = 0; dt < 4; ++dt)
#pragma unroll
        for (int r = 0; r < 16; ++r) acc[dt][r] *= corr;
      mrun = mn;
    }
    // exp in place (register diet: no separate ps[16])
    float rs = 0.f;
#pragma unroll
    for (int r = 0; r < 16; ++r) { sc[r] = fexp2(sc[r] - mrun); rs += sc[r]; }
    rs += __shfl_xor(rs, 32);
    lrun += rs;

    // ---- P -> bf16 PV B-operand fragments, in-register (T12)
    unsigned a0 = pk2(sc[0], sc[1]),   a1 = pk2(sc[2],  sc[3]);
    unsigned a2 = pk2(sc[4], sc[5]),   a3 = pk2(sc[6],  sc[7]);
    unsigned b0 = pk2(sc[8], sc[9]),   b1 = pk2(sc[10], sc[11]);
    unsigned b2 = pk2(sc[12], sc[13]), b3 = pk2(sc[14], sc[15]);
    asm("v_permlane32_swap_b32 %0, %1" : "+v"(a0), "+v"(a2));
    asm("v_permlane32_swap_b32 %0, %1" : "+v"(a1), "+v"(a3));
    asm("v_permlane32_swap_b32 %0, %1" : "+v"(b0), "+v"(b2));
    asm("v_permlane32_swap_b32 %0, %1" : "+v"(b1), "+v"(b3));
    u32x4 w0 = {a0, a1, a2, a3};
    u32x4 w1 = {b0, b1, b2, b3};
    bf16x8 pa0 = __builtin_bit_cast(bf16x8, w0);
    bf16x8 pa1 = __builtin_bit_cast(bf16x8, w1);

    // ---- PV: acc[dt] += V^T_frag . P ; A=V^T (rows d), B=P (col q)
    __builtin_amdgcn_s_setprio(1);
#pragma unroll
    for (int dt = 0; dt < 4; ++dt) {
      const int vs = (dt * 4 + (l31 >> 3)) & 15;
      bf16x8 vf0 = *reinterpret_cast<const bf16x8*>(
          &VL[cur][dt * 32 + l31][(((ksp << 2) | hi) ^ vs) * 8]);
      acc[dt] = __builtin_amdgcn_mfma_f32_32x32x16_bf16(vf0, pa0, acc[dt], 0, 0, 0);
      bf16x8 vf1 = *reinterpret_cast<const bf16x8*>(
          &VL[cur][dt * 32 + l31][(((ksp << 2) | 2 | hi) ^ vs) * 8]);
      acc[dt] = __builtin_amdgcn_mfma_f32_32x32x16_bf16(vf1, pa1, acc[dt], 0, 0, 0);
    }
    __builtin_amdgcn_s_setprio(0);

    if (pre) storeV(cur ^ 1);
    __syncthreads();
  }

  // ---- split-k merge (4-way) through LDS scratch, then coalesced O store
  float* scr = reinterpret_cast<float*>(smem);            // 8 regions x [32][132]
  float* mls = reinterpret_cast<float*>(smem + 135168);   // [4 qg][4 ksp][2][32]
  auto scrAt = [&](int reg, int q, int d) -> float& { return scr[reg * 4224 + q * 132 + d]; };
  auto mlAt  = [&](int qg_, int ksp_, int w, int q) -> float& {
    return mls[((qg_ * 4 + ksp_) * 2 + w) * 32 + q];
  };
  auto drow = [&](int r) { return (r & 3) + 8 * (r >> 2) + 4 * hi; };

  // R1: ksp 2,3 dump; everyone publishes (m,l)
  if (ksp >= 2) {
#pragma unroll
    for (int dt = 0; dt < 4; ++dt)
#pragma unroll
      for (int r = 0; r < 16; ++r)
        scrAt(qg + 4 * (ksp - 2), l31, dt * 32 + drow(r)) = acc[dt][r];
  }
  mlAt(qg, ksp, 0, l31) = mrun;
  mlAt(qg, ksp, 1, l31) = lrun;
  __syncthreads();
  if (ksp < 2) {
    const int p = ksp + 2;
    const float m2 = mlAt(qg, p, 0, l31), l2 = mlAt(qg, p, 1, l31);
    const float mm = fmaxf(mrun, m2);
    const float w1 = fexp2(mrun - mm), w2 = fexp2(m2 - mm);
#pragma unroll
    for (int dt = 0; dt < 4; ++dt)
#pragma unroll
      for (int r = 0; r < 16; ++r)
        acc[dt][r] = acc[dt][r] * w1 + scrAt(qg + 4 * (p - 2), l31, dt * 32 + drow(r)) * w2;
    lrun = lrun * w1 + l2 * w2;
    mrun = mm;
  }
  __syncthreads();
  // R2: ksp 1 dumps merged
  if (ksp == 1) {
#pragma unroll
    for (int dt = 0; dt < 4; ++dt)
#pragma unroll
      for (int r = 0; r < 16; ++r)
        scrAt(qg, l31, dt * 32 + drow(r)) = acc[dt][r];
    mlAt(qg, 1, 0, l31) = mrun;
    mlAt(qg, 1, 1, l31) = lrun;
  }
  __syncthreads();
  if (ksp == 0) {
    const float m2 = mlAt(qg, 1, 0, l31), l2 = mlAt(qg, 1, 1, l31);
    const float mm = fmaxf(mrun, m2);
    const float w1 = fexp2(mrun - mm), w2 = fexp2(m2 - mm);
    const float inv = 1.0f / (lrun * w1 + l2 * w2);
#pragma unroll
    for (int dt = 0; dt < 4; ++dt)
#pragma unroll
      for (int r = 0; r < 16; ++r) {
        const int d = dt * 32 + drow(r);
        scrAt(qg, l31, d) = (acc[dt][r] * w1 + scrAt(qg, l31, d) * w2) * inv;
      }
  }
  __syncthreads();
  // coalesced O store: 128q x 128d tile from scratch
#pragma unroll
  for (int i = 0; i < 4; ++i) {
    const int row = i * 32 + krow;
    float4 val = *reinterpret_cast<const float4*>(&scr[(row >> 5) * 4224 + (row & 31) * 132 + c4 * 4]);
    *reinterpret_cast<float4*>(&Ob[(size_t)(qtile * 128 + row) * kD + c4 * 4]) = val;
  }
}

} // namespace

extern "C" void kernel_launch(void* const* d_in, const int* in_sizes, int n_in,
                              void* d_out, int out_size, void* d_ws, size_t ws_size,
                              hipStream_t stream) {
  const float* Q = (const float*)d_in[0];
  const float* K = (const float*)d_in[1];
  const float* V = (const float*)d_in[2];
  float* O = (float*)d_out;
  (void)in_sizes; (void)n_in; (void)out_size; (void)d_ws; (void)ws_size;
  dim3 grid(256), block(1024);
  hipLaunchKernelGGL(attn_fwd, grid, block, 0, stream, Q, K, V, O);
}

// Round 5
// 91.462 us; speedup vs baseline: 1.4471x; 1.4471x over previous
//
#include <hip/hip_runtime.h>
#include <hip/hip_bf16.h>

namespace {

constexpr int kS  = 2048;
constexpr int kD  = 128;
constexpr int kKB = 128;             // kv rows per tile
constexpr int kNT = kS / kKB;        // 16 tiles
constexpr int kChunks = 2048;        // 16B chunks per (128x128 bf16) tile image
// ws images, per (batch,tile): 2048 chunks x 16B.
//  K chunk CH: k=CH>>4, s=CH&15 -> holds K[k][d8*8..+8], d8 = s ^ (k&15)
//  V chunk CH: d=CH>>4, s=CH&15 -> holds V[k8*8+j][d] j=0..7, k8 = s ^ (d&15)
constexpr size_t kImgUShorts = (size_t)16 * 16 * kChunks * 8;   // 4M ushorts = 8 MB

typedef __attribute__((ext_vector_type(8)))  short bf16x8;
typedef __attribute__((ext_vector_type(16))) float f32x16;
typedef __attribute__((ext_vector_type(4)))  unsigned int u32x4;

__device__ inline unsigned short f2bf(float f) {
  return __builtin_bit_cast(unsigned short, __float2bfloat16(f));
}
__device__ inline unsigned pk2(float lo, float hi) {
  return (unsigned)f2bf(lo) | ((unsigned)f2bf(hi) << 16);
}
__device__ inline float fexp2(float x) { return __builtin_amdgcn_exp2f(x); }

__device__ inline void gload_lds16(const void* g, void* l) {
  __builtin_amdgcn_global_load_lds(
      (const __attribute__((address_space(1))) unsigned int*)g,
      (__attribute__((address_space(3))) unsigned int*)l, 16, 0, 0);
}

// ---------------- pre-pass: f32 -> bf16, swizzled images ----------------
__global__ __launch_bounds__(256)
void convert_kv(const float* __restrict__ K, const float* __restrict__ V,
                unsigned short* __restrict__ Kws, unsigned short* __restrict__ Vws)
{
  const int tid = threadIdx.x;
  const int gid = blockIdx.x & 255;
  const int b = gid >> 4, t = gid & 15;
  if (blockIdx.x < 256) {
    // K image: no transpose, octet-permuted within each 256B row
    const float* src = K + ((size_t)b * kS + t * kKB) * kD;
    unsigned short* dst = Kws + (size_t)gid * kChunks * 8;
#pragma unroll
    for (int i = 0; i < 8; ++i) {
      const int CH = i * 256 + tid;
      const int k = CH >> 4, s = CH & 15;
      const int d8 = s ^ (k & 15);
      const float* p = src + (size_t)k * kD + d8 * 8;
      float4 a = *reinterpret_cast<const float4*>(p);
      float4 c = *reinterpret_cast<const float4*>(p + 4);
      bf16x8 o;
      o[0] = (short)f2bf(a.x); o[1] = (short)f2bf(a.y);
      o[2] = (short)f2bf(a.z); o[3] = (short)f2bf(a.w);
      o[4] = (short)f2bf(c.x); o[5] = (short)f2bf(c.y);
      o[6] = (short)f2bf(c.z); o[7] = (short)f2bf(c.w);
      *reinterpret_cast<bf16x8*>(dst + (size_t)CH * 8) = o;
    }
  } else {
    // V image: transpose via LDS, then octet-permuted rows of V^T
    __shared__ unsigned short VT[128 * 136];     // [d][k], pad 136 (272B rows, 16B-aligned)
    const float* src = V + ((size_t)b * kS + t * kKB) * kD;
#pragma unroll
    for (int i = 0; i < 16; ++i) {
      const int idx = i * 256 + tid;
      const int k = idx >> 5, d4 = idx & 31;
      float4 v = *reinterpret_cast<const float4*>(src + (size_t)k * kD + d4 * 4);
      VT[(d4 * 4 + 0) * 136 + k] = f2bf(v.x);
      VT[(d4 * 4 + 1) * 136 + k] = f2bf(v.y);
      VT[(d4 * 4 + 2) * 136 + k] = f2bf(v.z);
      VT[(d4 * 4 + 3) * 136 + k] = f2bf(v.w);
    }
    __syncthreads();
    unsigned short* dst = Vws + (size_t)gid * kChunks * 8;
#pragma unroll
    for (int i = 0; i < 8; ++i) {
      const int CH = i * 256 + tid;
      const int d = CH >> 4, s = CH & 15;
      const int k8 = s ^ (d & 15);
      bf16x8 v = *reinterpret_cast<const bf16x8*>(&VT[d * 136 + k8 * 8]);
      *reinterpret_cast<bf16x8*>(dst + (size_t)CH * 8) = v;
    }
  }
}

// ---------------- main attention kernel ----------------
__global__ __launch_bounds__(1024, 4)
void attn_fwd(const float* __restrict__ Q,
              const unsigned short* __restrict__ Kws,
              const unsigned short* __restrict__ Vws,
              float* __restrict__ O)
{
  __shared__ __align__(16) unsigned char smem[131072];  // K[2]@0, V[2]@65536 (32KB each)
  __shared__ float mls[4 * 4 * 2 * 32];

  const int tid  = threadIdx.x;
  const int wv   = tid >> 6;
  const int qg   = wv & 3;           // q-group: 32 q-rows
  const int ksp  = wv >> 2;          // k-split: 32 of 128 kv-rows
  const int lane = tid & 63;
  const int l31  = lane & 31;
  const int hi   = lane >> 5;
  const int m15  = l31 & 15;         // swizzle key (== row&15 for our rows)

  // XCD-locality: 2 batches per XCD
  const int bid   = blockIdx.x;
  const int xcd   = bid & 7;
  const int slot  = bid >> 3;
  const int batch = xcd * 2 + (slot >> 4);
  const int qtile = slot & 15;

  const float* Qb = Q + (size_t)batch * kS * kD;
  float*       Ob = O + (size_t)batch * kS * kD;
  const int qrow0 = qtile * 128 + qg * 32;

  auto stage = [&](int t, int buf) {
    const size_t base = ((size_t)(batch * 16 + t) * kChunks + wv * 128 + lane) * 8;
    unsigned char* kd = smem + buf * 32768 + wv * 2048;
    gload_lds16(Kws + base,           kd);
    gload_lds16(Kws + base + 64 * 8,  kd + 1024);
    unsigned char* vd = smem + 65536 + buf * 32768 + wv * 2048;
    gload_lds16(Vws + base,           vd);
    gload_lds16(Vws + base + 64 * 8,  vd + 1024);
  };

  stage(0, 0);

  // ---- Q fragments as MFMA B-operand: col q = l31, rows d = c*16 + hi*8 + e
  constexpr float kQScale = 0.08838834764831845f * 1.4426950408889634f; // 1/sqrt(128)*log2(e)
  bf16x8 qf[8];
#pragma unroll
  for (int c = 0; c < 8; ++c) {
    const float* p = Qb + (size_t)(qrow0 + l31) * kD + c * 16 + hi * 8;
    float4 a = *reinterpret_cast<const float4*>(p);
    float4 b = *reinterpret_cast<const float4*>(p + 4);
    bf16x8 f;
    f[0] = (short)f2bf(a.x * kQScale); f[1] = (short)f2bf(a.y * kQScale);
    f[2] = (short)f2bf(a.z * kQScale); f[3] = (short)f2bf(a.w * kQScale);
    f[4] = (short)f2bf(b.x * kQScale); f[5] = (short)f2bf(b.y * kQScale);
    f[6] = (short)f2bf(b.z * kQScale); f[7] = (short)f2bf(b.w * kQScale);
    qf[c] = f;
  }

  f32x16 acc[4];
#pragma unroll
  for (int dt = 0; dt < 4; ++dt)
#pragma unroll
    for (int r = 0; r < 16; ++r) acc[dt][r] = 0.f;
  float mrun = -1e30f, lrun = 0.f;

  __syncthreads();   // drains stage(0) vmcnt

  const unsigned short* Ksm = reinterpret_cast<const unsigned short*>(smem);
  const unsigned short* Vsm = reinterpret_cast<const unsigned short*>(smem + 65536);
  const int kRowBase = (ksp * 32 + l31) * 128;   // ushort units; row stride 256B

  for (int t = 0; t < kNT; ++t) {
    const int cur = t & 1;
    if (t + 1 < kNT) stage(t + 1, cur ^ 1);

    // ---- QK^T swapped: rows k in regs, col q = l31
    f32x16 sc;
#pragma unroll
    for (int r = 0; r < 16; ++r) sc[r] = 0.f;
    __builtin_amdgcn_s_setprio(1);
#pragma unroll
    for (int c = 0; c < 8; ++c) {
      const int s = ((c << 1) | hi) ^ m15;
      bf16x8 kf = *reinterpret_cast<const bf16x8*>(&Ksm[cur * 16384 + kRowBase + s * 8]);
      sc = __builtin_amdgcn_mfma_f32_32x32x16_bf16(kf, qf[c], sc, 0, 0, 0);
    }
    __builtin_amdgcn_s_setprio(0);

    // ---- lane-local online softmax
    float mt = sc[0];
#pragma unroll
    for (int r = 1; r < 16; ++r) mt = fmaxf(mt, sc[r]);
    mt = fmaxf(mt, __shfl_xor(mt, 32));
    const float growth = mt - mrun;
    if (!__all(growth <= 8.0f)) {              // T13 defer-max
      const float mn = fmaxf(mrun, mt);
      const float corr = fexp2(mrun - mn);
      lrun *= corr;
#pragma unroll
      for (int dt = 0; dt < 4; ++dt)
#pragma unroll
        for (int r = 0; r < 16; ++r) acc[dt][r] *= corr;
      mrun = mn;
    }
    float rs = 0.f;
#pragma unroll
    for (int r = 0; r < 16; ++r) { sc[r] = fexp2(sc[r] - mrun); rs += sc[r]; }
    rs += __shfl_xor(rs, 32);
    lrun += rs;

    // ---- P -> bf16 PV B-operand, in-register (T12)
    unsigned a0 = pk2(sc[0], sc[1]),   a1 = pk2(sc[2],  sc[3]);
    unsigned a2 = pk2(sc[4], sc[5]),   a3 = pk2(sc[6],  sc[7]);
    unsigned b0 = pk2(sc[8], sc[9]),   b1 = pk2(sc[10], sc[11]);
    unsigned b2 = pk2(sc[12], sc[13]), b3 = pk2(sc[14], sc[15]);
    asm("v_permlane32_swap_b32 %0, %1" : "+v"(a0), "+v"(a2));
    asm("v_permlane32_swap_b32 %0, %1" : "+v"(a1), "+v"(a3));
    asm("v_permlane32_swap_b32 %0, %1" : "+v"(b0), "+v"(b2));
    asm("v_permlane32_swap_b32 %0, %1" : "+v"(b1), "+v"(b3));
    u32x4 w0 = {a0, a1, a2, a3};
    u32x4 w1 = {b0, b1, b2, b3};
    bf16x8 pa0 = __builtin_bit_cast(bf16x8, w0);
    bf16x8 pa1 = __builtin_bit_cast(bf16x8, w1);

    // ---- PV: acc[dt] += V^T_frag . P
    const int s0 = ((ksp << 2) | hi) ^ m15;
    __builtin_amdgcn_s_setprio(1);
#pragma unroll
    for (int dt = 0; dt < 4; ++dt) {
      const int vRow = cur * 16384 + (dt * 32 + l31) * 128;
      bf16x8 vf0 = *reinterpret_cast<const bf16x8*>(&Vsm[vRow + s0 * 8]);
      acc[dt] = __builtin_amdgcn_mfma_f32_32x32x16_bf16(vf0, pa0, acc[dt], 0, 0, 0);
      bf16x8 vf1 = *reinterpret_cast<const bf16x8*>(&Vsm[vRow + (s0 ^ 2) * 8]);
      acc[dt] = __builtin_amdgcn_mfma_f32_32x32x16_bf16(vf1, pa1, acc[dt], 0, 0, 0);
    }
    __builtin_amdgcn_s_setprio(0);

    __syncthreads();
  }

  // ---- split-k merge (4-way) through LDS scratch, then coalesced O store
  float* scr = reinterpret_cast<float*>(smem);   // 8 regions x [32 q][128 d]
  auto scrAt = [&](int reg, int q, int d) -> float& { return scr[reg * 4096 + q * 128 + d]; };
  auto mlAt  = [&](int qg_, int ksp_, int w, int q) -> float& {
    return mls[((qg_ * 4 + ksp_) * 2 + w) * 32 + q];
  };
  auto drow = [&](int r) { return (r & 3) + 8 * (r >> 2) + 4 * hi; };

  if (ksp >= 2) {
#pragma unroll
    for (int dt = 0; dt < 4; ++dt)
#pragma unroll
      for (int r = 0; r < 16; ++r)
        scrAt(qg + 4 * (ksp - 2), l31, dt * 32 + drow(r)) = acc[dt][r];
  }
  mlAt(qg, ksp, 0, l31) = mrun;
  mlAt(qg, ksp, 1, l31) = lrun;
  __syncthreads();
  if (ksp < 2) {
    const int p = ksp + 2;
    const float m2 = mlAt(qg, p, 0, l31), l2 = mlAt(qg, p, 1, l31);
    const float mm = fmaxf(mrun, m2);
    const float w1 = fexp2(mrun - mm), w2 = fexp2(m2 - mm);
#pragma unroll
    for (int dt = 0; dt < 4; ++dt)
#pragma unroll
      for (int r = 0; r < 16; ++r)
        acc[dt][r] = acc[dt][r] * w1 + scrAt(qg + 4 * (p - 2), l31, dt * 32 + drow(r)) * w2;
    lrun = lrun * w1 + l2 * w2;
    mrun = mm;
  }
  __syncthreads();
  if (ksp == 1) {
#pragma unroll
    for (int dt = 0; dt < 4; ++dt)
#pragma unroll
      for (int r = 0; r < 16; ++r)
        scrAt(qg, l31, dt * 32 + drow(r)) = acc[dt][r];
    mlAt(qg, 1, 0, l31) = mrun;
    mlAt(qg, 1, 1, l31) = lrun;
  }
  __syncthreads();
  if (ksp == 0) {
    const float m2 = mlAt(qg, 1, 0, l31), l2 = mlAt(qg, 1, 1, l31);
    const float mm = fmaxf(mrun, m2);
    const float w1 = fexp2(mrun - mm), w2 = fexp2(m2 - mm);
    const float inv = 1.0f / (lrun * w1 + l2 * w2);
#pragma unroll
    for (int dt = 0; dt < 4; ++dt)
#pragma unroll
      for (int r = 0; r < 16; ++r) {
        const int d = dt * 32 + drow(r);
        scrAt(qg, l31, d) = (acc[dt][r] * w1 + scrAt(qg, l31, d) * w2) * inv;
      }
  }
  __syncthreads();
  const int krow = tid >> 5, c4 = tid & 31;
#pragma unroll
  for (int i = 0; i < 4; ++i) {
    const int row = i * 32 + krow;
    float4 val = *reinterpret_cast<const float4*>(&scr[(row >> 5) * 4096 + (row & 31) * 128 + c4 * 4]);
    *reinterpret_cast<float4*>(&Ob[(size_t)(qtile * 128 + row) * kD + c4 * 4]) = val;
  }
}

} // namespace

extern "C" void kernel_launch(void* const* d_in, const int* in_sizes, int n_in,
                              void* d_out, int out_size, void* d_ws, size_t ws_size,
                              hipStream_t stream) {
  const float* Q = (const float*)d_in[0];
  const float* K = (const float*)d_in[1];
  const float* V = (const float*)d_in[2];
  float* O = (float*)d_out;
  (void)in_sizes; (void)n_in; (void)out_size; (void)ws_size;

  unsigned short* Kws = (unsigned short*)d_ws;
  unsigned short* Vws = Kws + kImgUShorts;       // 8 MB offset; total ws use = 16 MB

  hipLaunchKernelGGL(convert_kv, dim3(512), dim3(256), 0, stream, K, V, Kws, Vws);
  hipLaunchKernelGGL(attn_fwd,   dim3(256), dim3(1024), 0, stream, Q, Kws, Vws, O);
}

// Round 6
// 63.521 us; speedup vs baseline: 2.0836x; 1.4399x over previous
//
#include <hip/hip_runtime.h>
#include <hip/hip_bf16.h>

namespace {

constexpr int kS  = 2048;
constexpr int kD  = 128;
constexpr int kKB = 128;             // kv rows per tile
constexpr int kNT = kS / kKB;        // 16 tiles
constexpr int kChunks = 2048;        // 16B chunks per (128x128 bf16) tile image
constexpr size_t kImgUShorts = (size_t)16 * 16 * kChunks * 8;   // 8 MB per image set

typedef __attribute__((ext_vector_type(8)))  short bf16x8;
typedef __attribute__((ext_vector_type(16))) float f32x16;
typedef __attribute__((ext_vector_type(4)))  unsigned int u32x4;

__device__ inline unsigned short f2bf(float f) {
  return __builtin_bit_cast(unsigned short, __float2bfloat16(f));
}
__device__ inline unsigned pk2(float lo, float hi) {
  return (unsigned)f2bf(lo) | ((unsigned)f2bf(hi) << 16);
}
__device__ inline float fexp2(float x) { return __builtin_amdgcn_exp2f(x); }

__device__ inline void gload_lds16(const void* g, void* l) {
  __builtin_amdgcn_global_load_lds(
      (const __attribute__((address_space(1))) unsigned int*)g,
      (__attribute__((address_space(3))) unsigned int*)l, 16, 0, 0);
}

// ---------------- pre-pass: f32 -> bf16, swizzled images ----------------
__global__ __launch_bounds__(256)
void convert_kv(const float* __restrict__ K, const float* __restrict__ V,
                unsigned short* __restrict__ Kws, unsigned short* __restrict__ Vws)
{
  const int tid = threadIdx.x;
  const int gid = blockIdx.x & 255;
  const int b = gid >> 4, t = gid & 15;
  if (blockIdx.x < 256) {
    // K image: row-major [k][slot], slot s holds d-octet d8 = s ^ (k&15)
    const float* src = K + ((size_t)b * kS + t * kKB) * kD;
    unsigned short* dst = Kws + (size_t)gid * kChunks * 8;
#pragma unroll
    for (int i = 0; i < 8; ++i) {
      const int CH = i * 256 + tid;
      const int k = CH >> 4, s = CH & 15;
      const int d8 = s ^ (k & 15);
      const float* p = src + (size_t)k * kD + d8 * 8;
      float4 a = *reinterpret_cast<const float4*>(p);
      float4 c = *reinterpret_cast<const float4*>(p + 4);
      bf16x8 o;
      o[0] = (short)f2bf(a.x); o[1] = (short)f2bf(a.y);
      o[2] = (short)f2bf(a.z); o[3] = (short)f2bf(a.w);
      o[4] = (short)f2bf(c.x); o[5] = (short)f2bf(c.y);
      o[6] = (short)f2bf(c.z); o[7] = (short)f2bf(c.w);
      *reinterpret_cast<bf16x8*>(dst + (size_t)CH * 8) = o;
    }
  } else {
    // V image: V^T rows [d][slot], slot s holds k-octet k8 = s ^ (d&15)
    __shared__ unsigned short VT[128 * 136];
    const float* src = V + ((size_t)b * kS + t * kKB) * kD;
#pragma unroll
    for (int i = 0; i < 16; ++i) {
      const int idx = i * 256 + tid;
      const int k = idx >> 5, d4 = idx & 31;
      float4 v = *reinterpret_cast<const float4*>(src + (size_t)k * kD + d4 * 4);
      VT[(d4 * 4 + 0) * 136 + k] = f2bf(v.x);
      VT[(d4 * 4 + 1) * 136 + k] = f2bf(v.y);
      VT[(d4 * 4 + 2) * 136 + k] = f2bf(v.z);
      VT[(d4 * 4 + 3) * 136 + k] = f2bf(v.w);
    }
    __syncthreads();
    unsigned short* dst = Vws + (size_t)gid * kChunks * 8;
#pragma unroll
    for (int i = 0; i < 8; ++i) {
      const int CH = i * 256 + tid;
      const int d = CH >> 4, s = CH & 15;
      const int k8 = s ^ (d & 15);
      bf16x8 v = *reinterpret_cast<const bf16x8*>(&VT[d * 136 + k8 * 8]);
      *reinterpret_cast<bf16x8*>(dst + (size_t)CH * 8) = v;
    }
  }
}

// ---------------- main attention kernel ----------------
// LDS map: K dbuf [0,65536), V dbuf [65536,131072), Q [131072,163840)
// merge phase overlays: scratch [0,131072), mls on dead Q region.
__global__ __launch_bounds__(1024, 4)
void attn_fwd(const float* __restrict__ Q,
              const unsigned short* __restrict__ Kws,
              const unsigned short* __restrict__ Vws,
              float* __restrict__ O)
{
  __shared__ __align__(16) unsigned char smem[163840];

  const int tid  = threadIdx.x;
  const int wv   = tid >> 6;
  const int qg   = wv & 3;           // q-group: 32 q-rows
  const int ksp  = wv >> 2;          // k-split: 32 of 128 kv-rows
  const int lane = tid & 63;
  const int l31  = lane & 31;
  const int hi   = lane >> 5;
  const int m15  = l31 & 15;

  // XCD-locality: 2 batches per XCD
  const int bid   = blockIdx.x;
  const int xcd   = bid & 7;
  const int slot  = bid >> 3;
  const int batch = xcd * 2 + (slot >> 4);
  const int qtile = slot & 15;

  const float* Qb = Q + (size_t)batch * kS * kD;
  float*       Ob = O + (size_t)batch * kS * kD;

  auto stage = [&](int t, int buf) {
    const size_t base = ((size_t)(batch * 16 + t) * kChunks + wv * 128 + lane) * 8;
    unsigned char* kd = smem + buf * 32768 + wv * 2048;
    gload_lds16(Kws + base,           kd);
    gload_lds16(Kws + base + 64 * 8,  kd + 1024);
    unsigned char* vd = smem + 65536 + buf * 32768 + wv * 2048;
    gload_lds16(Vws + base,           vd);
    gload_lds16(Vws + base + 64 * 8,  vd + 1024);
  };

  stage(0, 0);

  // ---- Q -> LDS (bf16, scaled, K-style swizzle: slot s holds d8 = s ^ (q&15))
  constexpr float kQScale = 0.08838834764831845f * 1.4426950408889634f; // 1/sqrt(128)*log2(e)
  {
    unsigned short* Qsm = reinterpret_cast<unsigned short*>(smem + 131072);
    const float* src = Qb + (size_t)(qtile * 128) * kD;
#pragma unroll
    for (int i = 0; i < 2; ++i) {
      const int idx = i * 1024 + tid;      // 0..2047
      const int q = idx >> 4, s = idx & 15;
      const int d8 = s ^ (q & 15);
      const float* p = src + (size_t)q * kD + d8 * 8;
      float4 a = *reinterpret_cast<const float4*>(p);
      float4 b = *reinterpret_cast<const float4*>(p + 4);
      bf16x8 f;
      f[0] = (short)f2bf(a.x * kQScale); f[1] = (short)f2bf(a.y * kQScale);
      f[2] = (short)f2bf(a.z * kQScale); f[3] = (short)f2bf(a.w * kQScale);
      f[4] = (short)f2bf(b.x * kQScale); f[5] = (short)f2bf(b.y * kQScale);
      f[6] = (short)f2bf(b.z * kQScale); f[7] = (short)f2bf(b.w * kQScale);
      *reinterpret_cast<bf16x8*>(&Qsm[(size_t)q * 128 + s * 8]) = f;
    }
  }

  f32x16 acc[4];
#pragma unroll
  for (int dt = 0; dt < 4; ++dt)
#pragma unroll
    for (int r = 0; r < 16; ++r) acc[dt][r] = 0.f;
  float mrun = -1e30f, lrun = 0.f;

  __syncthreads();   // drains stage(0) DMA + Q writes

  const unsigned short* Ksm = reinterpret_cast<const unsigned short*>(smem);
  const unsigned short* Vsm = reinterpret_cast<const unsigned short*>(smem + 65536);
  const unsigned short* Qsm = reinterpret_cast<const unsigned short*>(smem + 131072);
  const int kRowBase = (ksp * 32 + l31) * 128;   // ushort units, 256B rows
  const int qRowBase = (qg  * 32 + l31) * 128;

  for (int t = 0; t < kNT; ++t) {
    const int cur = t & 1;
    if (t + 1 < kNT) stage(t + 1, cur ^ 1);

    // ---- QK^T swapped: rows k in regs, col q = l31 (both operands from LDS)
    f32x16 sc;
#pragma unroll
    for (int r = 0; r < 16; ++r) sc[r] = 0.f;
    __builtin_amdgcn_s_setprio(1);
#pragma unroll
    for (int c = 0; c < 8; ++c) {
      const int s = ((c << 1) | hi) ^ m15;
      bf16x8 kf = *reinterpret_cast<const bf16x8*>(&Ksm[cur * 16384 + kRowBase + s * 8]);
      bf16x8 qf = *reinterpret_cast<const bf16x8*>(&Qsm[qRowBase + s * 8]);
      sc = __builtin_amdgcn_mfma_f32_32x32x16_bf16(kf, qf, sc, 0, 0, 0);
    }
    __builtin_amdgcn_s_setprio(0);

    // ---- lane-local online softmax
    float mt = sc[0];
#pragma unroll
    for (int r = 1; r < 16; ++r) mt = fmaxf(mt, sc[r]);
    mt = fmaxf(mt, __shfl_xor(mt, 32));
    const float growth = mt - mrun;
    if (!__all(growth <= 8.0f)) {              // T13 defer-max
      const float mn = fmaxf(mrun, mt);
      const float corr = fexp2(mrun - mn);
      lrun *= corr;
#pragma unroll
      for (int dt = 0; dt < 4; ++dt)
#pragma unroll
        for (int r = 0; r < 16; ++r) acc[dt][r] *= corr;
      mrun = mn;
    }
    float rs = 0.f;
#pragma unroll
    for (int r = 0; r < 16; ++r) { sc[r] = fexp2(sc[r] - mrun); rs += sc[r]; }
    rs += __shfl_xor(rs, 32);
    lrun += rs;

    // ---- P -> bf16 PV B-operand, in-register (T12)
    unsigned a0 = pk2(sc[0], sc[1]),   a1 = pk2(sc[2],  sc[3]);
    unsigned a2 = pk2(sc[4], sc[5]),   a3 = pk2(sc[6],  sc[7]);
    unsigned b0 = pk2(sc[8], sc[9]),   b1 = pk2(sc[10], sc[11]);
    unsigned b2 = pk2(sc[12], sc[13]), b3 = pk2(sc[14], sc[15]);
    asm("v_permlane32_swap_b32 %0, %1" : "+v"(a0), "+v"(a2));
    asm("v_permlane32_swap_b32 %0, %1" : "+v"(a1), "+v"(a3));
    asm("v_permlane32_swap_b32 %0, %1" : "+v"(b0), "+v"(b2));
    asm("v_permlane32_swap_b32 %0, %1" : "+v"(b1), "+v"(b3));
    u32x4 w0 = {a0, a1, a2, a3};
    u32x4 w1 = {b0, b1, b2, b3};
    bf16x8 pa0 = __builtin_bit_cast(bf16x8, w0);
    bf16x8 pa1 = __builtin_bit_cast(bf16x8, w1);

    // ---- PV: acc[dt] += V^T_frag . P
    const int s0 = ((ksp << 2) | hi) ^ m15;
    __builtin_amdgcn_s_setprio(1);
#pragma unroll
    for (int dt = 0; dt < 4; ++dt) {
      const int vRow = cur * 16384 + (dt * 32 + l31) * 128;
      bf16x8 vf0 = *reinterpret_cast<const bf16x8*>(&Vsm[vRow + s0 * 8]);
      acc[dt] = __builtin_amdgcn_mfma_f32_32x32x16_bf16(vf0, pa0, acc[dt], 0, 0, 0);
      bf16x8 vf1 = *reinterpret_cast<const bf16x8*>(&Vsm[vRow + (s0 ^ 2) * 8]);
      acc[dt] = __builtin_amdgcn_mfma_f32_32x32x16_bf16(vf1, pa1, acc[dt], 0, 0, 0);
    }
    __builtin_amdgcn_s_setprio(0);

    __syncthreads();
  }

  // ---- split-k merge (4-way); scratch overlays K/V staging, swizzled banks
  float* scr = reinterpret_cast<float*>(smem);              // 8 regions x [32 q][128 d]
  float* mls = reinterpret_cast<float*>(smem + 131072);     // overlays dead Q region
  auto scrAt = [&](int reg, int q, int d) -> float& {
    return scr[reg * 4096 + q * 128 + (d ^ ((q & 7) << 2))];
  };
  auto mlAt  = [&](int qg_, int ksp_, int w, int q) -> float& {
    return mls[((qg_ * 4 + ksp_) * 2 + w) * 32 + q];
  };
  auto drow = [&](int r) { return (r & 3) + 8 * (r >> 2) + 4 * hi; };

  if (ksp >= 2) {
#pragma unroll
    for (int dt = 0; dt < 4; ++dt)
#pragma unroll
      for (int r = 0; r < 16; ++r)
        scrAt(qg + 4 * (ksp - 2), l31, dt * 32 + drow(r)) = acc[dt][r];
  }
  mlAt(qg, ksp, 0, l31) = mrun;
  mlAt(qg, ksp, 1, l31) = lrun;
  __syncthreads();
  if (ksp < 2) {
    const int p = ksp + 2;
    const float m2 = mlAt(qg, p, 0, l31), l2 = mlAt(qg, p, 1, l31);
    const float mm = fmaxf(mrun, m2);
    const float w1 = fexp2(mrun - mm), w2 = fexp2(m2 - mm);
#pragma unroll
    for (int dt = 0; dt < 4; ++dt)
#pragma unroll
      for (int r = 0; r < 16; ++r)
        acc[dt][r] = acc[dt][r] * w1 + scrAt(qg + 4 * (p - 2), l31, dt * 32 + drow(r)) * w2;
    lrun = lrun * w1 + l2 * w2;
    mrun = mm;
  }
  __syncthreads();
  if (ksp == 1) {
#pragma unroll
    for (int dt = 0; dt < 4; ++dt)
#pragma unroll
      for (int r = 0; r < 16; ++r)
        scrAt(qg, l31, dt * 32 + drow(r)) = acc[dt][r];
    mlAt(qg, 1, 0, l31) = mrun;
    mlAt(qg, 1, 1, l31) = lrun;
  }
  __syncthreads();
  if (ksp == 0) {
    const float m2 = mlAt(qg, 1, 0, l31), l2 = mlAt(qg, 1, 1, l31);
    const float mm = fmaxf(mrun, m2);
    const float w1 = fexp2(mrun - mm), w2 = fexp2(m2 - mm);
    const float inv = 1.0f / (lrun * w1 + l2 * w2);
#pragma unroll
    for (int dt = 0; dt < 4; ++dt)
#pragma unroll
      for (int r = 0; r < 16; ++r) {
        const int d = dt * 32 + drow(r);
        scrAt(qg, l31, d) = (acc[dt][r] * w1 + scrAt(qg, l31, d) * w2) * inv;
      }
  }
  __syncthreads();
  const int krow = tid >> 5, c4 = tid & 31;
#pragma unroll
  for (int i = 0; i < 4; ++i) {
    const int row = i * 32 + krow;
    const int q = row & 31;
    float4 val = *reinterpret_cast<const float4*>(
        &scr[(row >> 5) * 4096 + q * 128 + ((c4 * 4) ^ ((q & 7) << 2))]);
    *reinterpret_cast<float4*>(&Ob[(size_t)(qtile * 128 + row) * kD + c4 * 4]) = val;
  }
}

} // namespace

extern "C" void kernel_launch(void* const* d_in, const int* in_sizes, int n_in,
                              void* d_out, int out_size, void* d_ws, size_t ws_size,
                              hipStream_t stream) {
  const float* Q = (const float*)d_in[0];
  const float* K = (const float*)d_in[1];
  const float* V = (const float*)d_in[2];
  float* O = (float*)d_out;
  (void)in_sizes; (void)n_in; (void)out_size; (void)ws_size;

  unsigned short* Kws = (unsigned short*)d_ws;
  unsigned short* Vws = Kws + kImgUShorts;

  hipLaunchKernelGGL(convert_kv, dim3(512), dim3(256), 0, stream, K, V, Kws, Vws);
  hipLaunchKernelGGL(attn_fwd,   dim3(256), dim3(1024), 0, stream, Q, Kws, Vws, O);
}